// Round 1
// baseline (6318.311 us; speedup 1.0000x reference)
//
#include <hip/hip_runtime.h>
#include <math.h>

// Problem constants (fixed by the reference)
#define TDIM  512
#define NB    2
#define SLEN  2048
#define VOCAB 32000
#define NLAYER 3
#define NROW  (NB * SLEN)            // 4096 rows of activations

static const long SD  = (long)SLEN * TDIM;   // per-batch activation stride
static const long ST  = (long)SLEN * SLEN;   // per-batch score stride
static const long ACT = (long)NB * SLEN * TDIM;
static const long DD  = (long)TDIM * TDIM;

// ---------------- block reduction helpers (256 threads = 4 waves) ----------
__device__ __forceinline__ float blockSum256(float v) {
    #pragma unroll
    for (int o = 32; o > 0; o >>= 1) v += __shfl_down(v, o);
    __shared__ float sm[4];
    __syncthreads();
    if ((threadIdx.x & 63) == 0) sm[threadIdx.x >> 6] = v;
    __syncthreads();
    return sm[0] + sm[1] + sm[2] + sm[3];
}

__device__ __forceinline__ float blockMax256(float v) {
    #pragma unroll
    for (int o = 32; o > 0; o >>= 1) v = fmaxf(v, __shfl_down(v, o));
    __shared__ float sm[4];
    __syncthreads();
    if ((threadIdx.x & 63) == 0) sm[threadIdx.x >> 6] = v;
    __syncthreads();
    return fmaxf(fmaxf(sm[0], sm[1]), fmaxf(sm[2], sm[3]));
}

// ---------------- fp32 tiled GEMM -----------------------------------------
// C[bm..][bn..] = alpha * A·B (+bias). TB=false: B is K x N (ldb).
// TB=true: B is N x K (ldb), computes A·B^T. Batched via blockIdx.z strides.
// Requires M%64==0, N%64==0, K%16==0 (true for all shapes here).
template<bool TB, bool BIAS>
__global__ __launch_bounds__(256)
void gemm_f32(const float* __restrict__ A, const float* __restrict__ B,
              const float* __restrict__ bias, float* __restrict__ C,
              int K, int lda, int ldb, int ldc,
              long sA, long sB, long sC, float alpha)
{
    __shared__ float As[16][64];   // As[k][m]
    __shared__ float Bs[16][64];   // Bs[k][n]
    A += (long)blockIdx.z * sA;
    B += (long)blockIdx.z * sB;
    C += (long)blockIdx.z * sC;
    const int bm = blockIdx.y << 6, bn = blockIdx.x << 6;
    const int tid = threadIdx.x;
    const int tx = (tid & 15) << 2;          // n micro-tile offset
    const int ty = (tid >> 4) << 2;          // m micro-tile offset
    const int ar = tid >> 2, ac = (tid & 3) << 2;   // A-tile load coords
    const int br = tid >> 4, bc = (tid & 15) << 2;  // B-tile (NN) load coords
    float acc[4][4] = {};
    for (int k0 = 0; k0 < K; k0 += 16) {
        float4 a4 = *(const float4*)(A + (long)(bm + ar) * lda + (k0 + ac));
        As[ac + 0][ar] = a4.x; As[ac + 1][ar] = a4.y;
        As[ac + 2][ar] = a4.z; As[ac + 3][ar] = a4.w;
        if (!TB) {
            float4 b4 = *(const float4*)(B + (long)(k0 + br) * ldb + (bn + bc));
            *(float4*)(&Bs[br][bc]) = b4;
        } else {
            float4 b4 = *(const float4*)(B + (long)(bn + ar) * ldb + (k0 + ac));
            Bs[ac + 0][ar] = b4.x; Bs[ac + 1][ar] = b4.y;
            Bs[ac + 2][ar] = b4.z; Bs[ac + 3][ar] = b4.w;
        }
        __syncthreads();
        #pragma unroll
        for (int k = 0; k < 16; ++k) {
            float4 av = *(const float4*)(&As[k][ty]);   // ds_read_b128
            float4 bv = *(const float4*)(&Bs[k][tx]);
            float am[4] = {av.x, av.y, av.z, av.w};
            float bb[4] = {bv.x, bv.y, bv.z, bv.w};
            #pragma unroll
            for (int i = 0; i < 4; ++i)
                #pragma unroll
                for (int j = 0; j < 4; ++j)
                    acc[i][j] = fmaf(am[i], bb[j], acc[i][j]);
        }
        __syncthreads();
    }
    #pragma unroll
    for (int i = 0; i < 4; ++i) {
        float4 o;
        o.x = acc[i][0] * alpha; o.y = acc[i][1] * alpha;
        o.z = acc[i][2] * alpha; o.w = acc[i][3] * alpha;
        if (BIAS) {
            o.x += bias[bn + tx + 0]; o.y += bias[bn + tx + 1];
            o.z += bias[bn + tx + 2]; o.w += bias[bn + tx + 3];
        }
        *(float4*)(C + (long)(bm + ty + i) * ldc + (bn + tx)) = o;
    }
}

// ---------------- softmax over rows of 2048 (attention scores) -------------
__global__ __launch_bounds__(256)
void softmax2048(float* __restrict__ s)
{
    long row = blockIdx.x;
    float* p = s + row * (long)SLEN;
    int t = threadIdx.x;
    float v[8], m = -INFINITY;
    #pragma unroll
    for (int i = 0; i < 8; ++i) { v[i] = p[t + 256 * i]; m = fmaxf(m, v[i]); }
    m = blockMax256(m);
    float sum = 0.f;
    #pragma unroll
    for (int i = 0; i < 8; ++i) { v[i] = expf(v[i] - m); sum += v[i]; }
    sum = blockSum256(sum);
    float inv = 1.0f / sum;
    #pragma unroll
    for (int i = 0; i < 8; ++i) p[t + 256 * i] = v[i] * inv;
}

// ---------------- softmax over rows of 32000 (vocab), in place -------------
__global__ __launch_bounds__(256)
void softmax_vocab(float* __restrict__ out)
{
    long row = blockIdx.x;
    float* p = out + row * (long)VOCAB;
    int t = threadIdx.x;
    // online max+sum in one read pass
    float m = -INFINITY, s = 0.f;
    for (int i = t; i < VOCAB; i += 256) {
        float x = p[i];
        if (x > m) { s *= expf(m - x); m = x; }
        s += expf(x - m);
    }
    #pragma unroll
    for (int o = 32; o > 0; o >>= 1) {
        float m2 = __shfl_down(m, o), s2 = __shfl_down(s, o);
        float M = fmaxf(m, m2);
        s = s * expf(m - M) + s2 * expf(m2 - M);
        m = M;
    }
    __shared__ float sm[4], ss[4];
    if ((t & 63) == 0) { sm[t >> 6] = m; ss[t >> 6] = s; }
    __syncthreads();
    float M = fmaxf(fmaxf(sm[0], sm[1]), fmaxf(sm[2], sm[3]));
    float S = ss[0] * expf(sm[0] - M) + ss[1] * expf(sm[1] - M)
            + ss[2] * expf(sm[2] - M) + ss[3] * expf(sm[3] - M);
    float inv = 1.0f / S;
    for (int i = t; i < VOCAB; i += 256) p[i] = expf(p[i] - M) * inv;
}

// ---------------- fused residual + (silu) + layernorm ----------------------
// MODE 0: y = LN(a + r)                (non-affine, attention epilogue)
// MODE 1: y = LN(silu(a) + r) * g + b  (FFN epilogue)
// One block per row of TDIM=512; safe when y aliases r (reads before writes,
// separated by the reduction barriers).
template<int MODE>
__global__ __launch_bounds__(256)
void ln_row(const float* __restrict__ a, const float* __restrict__ r,
            const float* __restrict__ g, const float* __restrict__ b,
            float* __restrict__ y)
{
    long row = blockIdx.x;
    const float* pa = a + row * (long)TDIM;
    const float* pr = r + row * (long)TDIM;
    float* py = y + row * (long)TDIM;
    int t = threadIdx.x;
    float v0 = pa[t], v1 = pa[t + 256];
    if (MODE == 1) {
        v0 = v0 / (1.0f + expf(-v0));
        v1 = v1 / (1.0f + expf(-v1));
    }
    v0 += pr[t]; v1 += pr[t + 256];
    float mean = blockSum256(v0 + v1) * (1.0f / TDIM);
    float d0 = v0 - mean, d1 = v1 - mean;
    float var = blockSum256(d0 * d0 + d1 * d1) * (1.0f / TDIM);
    float inv = rsqrtf(var + 1e-5f);
    float y0 = d0 * inv, y1 = d1 * inv;
    if (MODE == 1) {
        y0 = y0 * g[t] + b[t];
        y1 = y1 * g[t + 256] + b[t + 256];
    }
    py[t] = y0; py[t + 256] = y1;
}

// ---------------- host-side orchestration ----------------------------------
extern "C" void kernel_launch(void* const* d_in, const int* in_sizes, int n_in,
                              void* d_out, int out_size, void* d_ws, size_t ws_size,
                              hipStream_t stream)
{
    (void)in_sizes; (void)n_in; (void)out_size; (void)ws_size;
    const float* X   = (const float*)d_in[0];
    const float* Y   = (const float*)d_in[1];
    const float* EWQ = (const float*)d_in[2];
    const float* EWK = (const float*)d_in[3];
    const float* EWV = (const float*)d_in[4];
    const float* EFW = (const float*)d_in[5];
    const float* EFB = (const float*)d_in[6];
    const float* EG  = (const float*)d_in[7];
    const float* EB  = (const float*)d_in[8];
    const float* DSQ = (const float*)d_in[9];
    const float* DSK = (const float*)d_in[10];
    const float* DSV = (const float*)d_in[11];
    const float* DCQ = (const float*)d_in[12];
    const float* DCK = (const float*)d_in[13];
    const float* DCV = (const float*)d_in[14];
    const float* DFW = (const float*)d_in[15];
    const float* DFB = (const float*)d_in[16];
    const float* DG  = (const float*)d_in[17];
    const float* DB  = (const float*)d_in[18];
    const float* FCW = (const float*)d_in[19];
    float* OUT = (float*)d_out;
    float* ws  = (float*)d_ws;

    // workspace layout: 8 activation buffers (8 MB each) + scores (32 MB) = 96 MB
    float* bx  = ws;          // encoder state / encoder output
    float* bq  = bx  + ACT;
    float* bk  = bq  + ACT;
    float* bv  = bk  + ACT;
    float* bt  = bv  + ACT;   // attn/ffn pre-LN temp
    float* bh1 = bt  + ACT;   // decoder self-attn out
    float* bh2 = bh1 + ACT;   // decoder cross-attn out
    float* bo  = bh2 + ACT;   // decoder running state
    float* bs  = bo  + ACT;   // scores [NB, SLEN, SLEN]

    hipMemcpyAsync(bx, X, ACT * sizeof(float), hipMemcpyDeviceToDevice, stream);

    dim3 blk(256);
    // projection: [4096,512] @ [512,512] (same weights for both batches)
    auto proj = [&](const float* A, const float* W, float* C) {
        dim3 g(TDIM / 64, NROW / 64, 1);
        gemm_f32<false, false><<<g, blk, 0, stream>>>(
            A, W, nullptr, C, TDIM, TDIM, TDIM, TDIM, 0, 0, 0, 1.0f);
    };
    // full single-head attention: dst = LN(softmax(xq Wq (ctx Wk)^T / 8) ctx Wv + xq)
    auto attn = [&](const float* xq, const float* ctx,
                    const float* wq, const float* wk, const float* wv, float* dst) {
        proj(xq,  wq, bq);
        proj(ctx, wk, bk);
        proj(ctx, wv, bv);
        {   // scores = q k^T / 8, batched
            dim3 g(SLEN / 64, SLEN / 64, NB);
            gemm_f32<true, false><<<g, blk, 0, stream>>>(
                bq, bk, nullptr, bs, TDIM, TDIM, TDIM, SLEN, SD, SD, ST, 0.125f);
        }
        softmax2048<<<dim3(NROW), blk, 0, stream>>>(bs);
        {   // pv = p @ v, batched
            dim3 g(TDIM / 64, SLEN / 64, NB);
            gemm_f32<false, false><<<g, blk, 0, stream>>>(
                bs, bv, nullptr, bt, SLEN, SLEN, TDIM, TDIM, ST, SD, SD, 1.0f);
        }
        ln_row<0><<<dim3(NROW), blk, 0, stream>>>(bt, xq, nullptr, nullptr, dst);
    };
    auto ffn = [&](const float* xin, const float* fw, const float* fb,
                   const float* g_, const float* b_, float* dst) {
        dim3 g(TDIM / 64, NROW / 64, 1);
        gemm_f32<false, true><<<g, blk, 0, stream>>>(
            xin, fw, fb, bt, TDIM, TDIM, TDIM, TDIM, 0, 0, 0, 1.0f);
        ln_row<1><<<dim3(NROW), blk, 0, stream>>>(bt, xin, g_, b_, dst);
    };

    // ---- encoder ----
    for (int i = 0; i < NLAYER; ++i) {
        attn(bx, bx, EWQ + i * DD, EWK + i * DD, EWV + i * DD, bx);
        ffn(bx, EFW + i * DD, EFB + i * TDIM, EG + i * TDIM, EB + i * TDIM, bx);
    }

    // ---- decoder ----
    hipMemcpyAsync(bo, Y, ACT * sizeof(float), hipMemcpyDeviceToDevice, stream);
    for (int i = 0; i < NLAYER; ++i) {
        attn(bx,  bx, DSQ + i * DD, DSK + i * DD, DSV + i * DD, bh1); // self-attn on enc out
        attn(bh1, bo, DCQ + i * DD, DCK + i * DD, DCV + i * DD, bh2); // cross-attn, K/V from state
        ffn(bh2, DFW + i * DD, DFB + i * TDIM, DG + i * TDIM, DB + i * TDIM, bo);
    }

    // ---- final projection to vocab (written straight into d_out) + softmax ----
    {
        dim3 g(VOCAB / 64, NROW / 64, 1);
        gemm_f32<false, false><<<g, blk, 0, stream>>>(
            bo, FCW, nullptr, OUT, TDIM, TDIM, VOCAB, VOCAB, 0, 0, 0, 1.0f);
    }
    softmax_vocab<<<dim3(NROW), blk, 0, stream>>>(OUT);
}